// Round 17
// baseline (94.520 us; speedup 1.0000x reference)
//
#include <hip/hip_runtime.h>
#include <hip/hip_bf16.h>
#include <math.h>

#define N_SAMPLES 32768
#define STEP 256
#define N_FRAMES 128
#define N_COEFFS 257
#define KT 576            // stacked K: 288 (cos) + 288 (sin)
#define NKS 18            // K-steps of 32
#define CPD 16
#define N_RES 32
#define EXPR 4
#define CTRL 128
#define NBN 8
#define BSTR 40           // padded Bs row stride (shorts): 80B -> 8 bank phases
#define PI_F 3.14159265358979323846f

typedef __attribute__((ext_vector_type(8))) short bf16x8;
typedef __attribute__((ext_vector_type(4))) float f32x4;

__device__ __forceinline__ unsigned short f2bf(float x) {
    __hip_bfloat16 h = __float2bfloat16(x);
    return *(unsigned short*)&h;
}

__device__ __forceinline__ float ftanh(float x) {
    // tanh(x) = 1 - 2/(exp2(2*log2(e)*x) + 1); hw exp2 + hw rcp, ~1e-6 abs err
    float e = exp2f(x * 2.885390081777927f);
    return 1.0f - 2.0f * __builtin_amdgcn_rcpf(e + 1.0f);
}

// ---------------------------------------------------------------- K1m v6: self-contained MFMA GEMM (+ zero out_summed)
__global__ __launch_bounds__(256) void k1m(const float* __restrict__ amp,
                                           const float* __restrict__ phase,
                                           const float* __restrict__ decay,
                                           float* __restrict__ res_raw,
                                           float* __restrict__ normp,
                                           float* __restrict__ out_zero) {
    __shared__ __align__(16) short Bs[2][64 * BSTR];   // 2 x 5120B, stride-40 rows
    __shared__ __align__(16) float Pl[KT];
    __shared__ __align__(16) float Zl[KT];
    __shared__ __align__(16) float Ll[KT];
    __shared__ float red[256];
    int tid = threadIdx.x;
    int l = tid & 63, w = tid >> 6;
    int bid = blockIdx.x;             // 1024, XCD-swizzled on re
    // zero the tanh-sum output for this call (1024*256 == NBN*N_SAMPLES)
    out_zero[(size_t)bid * 256 + tid] = 0.f;
    int x = bid & 7, m = bid >> 3;
    int re = x * 16 + (m >> 3);
    int sub = m & 7;
    int bx = sub >> 1, jb = sub & 1;
    int r = re >> 2, e = re & 3;

    for (int k = tid; k < KT; k += 256) {
        int kk = (k < 288) ? k : k - 288;
        float P = 0.f, Z = 0.f, L2v = 0.f;
        if (kk < N_COEFFS) {
            int src = (r * N_COEFFS + kk) * EXPR + e;
            float mm = fabsf(amp[src]) + 1e-12f;
            float ph = tanhf(phase[src]) * PI_F;
            float sg = 1.0f / (1.0f + expf(-decay[src]));
            float d  = 0.5f + 0.45f * sg;
            float wk = (kk == 0 || kk == 256) ? (1.0f / 512.0f) : (2.0f / 512.0f);
            float c  = (k < 288) ? (wk * mm * cosf(ph)) : (-wk * mm * sinf(ph));
            float sgn = (kk & 1) ? -1.f : 1.f;
            P = c * (d + sgn);
            Z = c * d;
            L2v = log2f(d);
        }
        Pl[k] = P; Zl[k] = Z; Ll[k] = L2v;
    }
    __syncthreads();

    int o = (bx * 4 + w) * 16 + (l & 15);
    int g4v = l >> 4;
    float cb[8], sb[8], cc[8], sc[8];
    #pragma unroll
    for (int ee = 0; ee < 8; ++ee) {
        int delta = ((ee >> 2) << 4) + (g4v << 2) + (ee & 3);
        float ang = (float)((delta * o) & 511) * (2.0f * PI_F / 512.0f);
        sincosf(ang, &sb[ee], &cb[ee]);
        cc[ee] = cb[ee]; sc[ee] = sb[ee];
    }
    float rc, rs;
    {
        float ang = (float)((32 * o) & 511) * (2.0f * PI_F / 512.0f);
        sincosf(ang, &rs, &rc);
    }

    int gj = tid >> 2;
    int gg = tid & 3;
    int jf = jb * 64 + gj;
    float jf_f = (float)jf;

    f32x4 acc[4] = {{0.f,0.f,0.f,0.f},{0.f,0.f,0.f,0.f},{0.f,0.f,0.f,0.f},{0.f,0.f,0.f,0.f}};
    int rrow = l & 15;
    int rcol = (l >> 4) * 8;

    auto GEN = [&](int s, int buf) {
        int kb = s * 32 + gg * 4;
        f32x4 p0 = *(const f32x4*)&Pl[kb];
        f32x4 p1 = *(const f32x4*)&Pl[kb + 16];
        f32x4 z0 = *(const f32x4*)&Zl[kb];
        f32x4 z1 = *(const f32x4*)&Zl[kb + 16];
        f32x4 l0 = *(const f32x4*)&Ll[kb];
        f32x4 l1 = *(const f32x4*)&Ll[kb + 16];
        bf16x8 vv;
        #pragma unroll
        for (int q = 0; q < 4; ++q) {
            float v0 = (jf == 0) ? z0[q] : p0[q] * exp2f(jf_f * l0[q]);
            float v1 = (jf == 0) ? z1[q] : p1[q] * exp2f(jf_f * l1[q]);
            vv[q]     = (short)f2bf(v0);
            vv[4 + q] = (short)f2bf(v1);
        }
        *(bf16x8*)&Bs[buf][gj * BSTR + gg * 8] = vv;
    };

    GEN(0, 0);
    __syncthreads();
    #pragma unroll
    for (int s = 0; s < NKS; ++s) {
        if (s < NKS - 1) GEN(s + 1, (s + 1) & 1);
        if (s == 9) {
            #pragma unroll
            for (int ee = 0; ee < 8; ++ee) { cc[ee] = cb[ee]; sc[ee] = sb[ee]; }
        }
        bf16x8 af;
        #pragma unroll
        for (int ee = 0; ee < 8; ++ee)
            af[ee] = (short)f2bf((s < 9) ? cc[ee] : sc[ee]);
        if (s != 8 && s != NKS - 1) {
            #pragma unroll
            for (int ee = 0; ee < 8; ++ee) {
                float t = cc[ee] * rc - sc[ee] * rs;
                sc[ee] = fmaf(cc[ee], rs, sc[ee] * rc);
                cc[ee] = t;
            }
        }
        const short* bp = &Bs[s & 1][0];
        #pragma unroll
        for (int jt = 0; jt < 4; ++jt) {
            bf16x8 bf = *(const bf16x8*)(bp + (jt * 16 + rrow) * BSTR + rcol);
            acc[jt] = __builtin_amdgcn_mfma_f32_16x16x32_bf16(af, bf, acc[jt], 0, 0, 0);
        }
        __syncthreads();
    }

    int otile = bx * 4 + w;
    int o0 = otile * 16 + ((l >> 4) & 3) * 4;
    int jbase = jb * 64 + (l & 15);
    float s2 = 0.f;
    #pragma unroll
    for (int jt = 0; jt < 4; ++jt) {
        int j = jbase + jt * 16;
        float4 v = make_float4(acc[jt][0], acc[jt][1], acc[jt][2], acc[jt][3]);
        s2 += v.x * v.x + v.y * v.y + v.z * v.z + v.w * v.w;
        *(float4*)&res_raw[(size_t)re * N_SAMPLES + j * STEP + o0] = v;
    }
    red[tid] = s2;
    __syncthreads();
    for (int st = 128; st > 0; st >>= 1) {
        if (tid < st) red[tid] += red[tid + st];
        __syncthreads();
    }
    if (tid == 0) normp[re * 8 + bx * 2 + jb] = red[0];
}

// ---------------------------------------------------------------- K3 v5: sliding-register FIR | route role (out_w)
__global__ __launch_bounds__(256) void k3_impconv(const float* __restrict__ res_raw,
                                                  const float* __restrict__ normp,
                                                  const float* __restrict__ noise,
                                                  const float* __restrict__ control,
                                                  const float* __restrict__ router,
                                                  float* __restrict__ out_w,
                                                  uint4* __restrict__ Gbf_q) {
    __shared__ __align__(16) float st[8320];
    __shared__ __align__(16) float imp[128];
    int bid = blockIdx.x;                 // 640 = 512 FIR (XCD-swizzled on r) + 128 route
    int tid = threadIdx.x;
    if (bid >= 512) {
        int idx = (bid - 512) * 256 + tid;
        int f  = idx % CTRL;
        int r  = (idx / CTRL) % N_RES;
        int bn = idx / (CTRL * N_RES);
        float s = 0.f;
        #pragma unroll
        for (int c = 0; c < CPD; ++c)
            s += control[(bn * CPD + c) * CTRL + f] * router[c * N_RES + r];
        out_w[idx] = s;
        return;
    }
    int r  = (bid & 7) * 4 + ((bid >> 3) & 3);
    int t2 = bid >> 5;
    int e  = t2 & 3;
    int kt = t2 >> 2;
    int re = r * 4 + e;
    float ns = 0.f;
    #pragma unroll
    for (int i = 0; i < 8; ++i) ns += normp[re * 8 + i];
    float inv = 1.0f / (sqrtf(ns) + 1e-8f);
    if (tid < 128)
        imp[tid] = (0.54f - 0.46f * cosf((2.0f * PI_F / 128.0f) * (float)tid)) * noise[tid];
    const float* rp = res_raw + (size_t)re * N_SAMPLES;
    int gbase = kt * 8192 - 127;
    for (int i = tid; i < 8320; i += 256) {
        int g = gbase + i;
        st[i] = (g >= 0 && g < N_SAMPLES) ? rp[g] * inv : 0.f;
    }
    __syncthreads();

    int jg = tid >> 6;
    int o0 = (tid & 63) * 4;
    int jl[8];
    #pragma unroll
    for (int hh = 0; hh < 4; ++hh) {
        int h = jg * 4 + hh;
        int j0 = ((h >> 1) & 1) * 16 + (h >> 2) * 4 + (h & 1) * 2;
        jl[2 * hh] = j0;
        jl[2 * hh + 1] = j0 + 1;
    }
    float4 cur[8];
    float acc[8][4] = {};
    #pragma unroll
    for (int w = 0; w < 8; ++w)
        cur[w] = *(const float4*)&st[jl[w] * 256 + o0];

    for (int v = 0; v < 128; v += 4) {
        float4 im = *(const float4*)&imp[124 - v];
        float wt[4] = {im.w, im.z, im.y, im.x};
        #pragma unroll
        for (int w = 0; w < 8; ++w) {
            float4 nx = *(const float4*)&st[jl[w] * 256 + o0 + v + 4];
            float win[8] = {cur[w].x, cur[w].y, cur[w].z, cur[w].w, nx.x, nx.y, nx.z, nx.w};
            #pragma unroll
            for (int k = 0; k < 4; ++k)
                #pragma unroll
                for (int d = 0; d < 4; ++d)
                    acc[w][d] = fmaf(wt[k], win[d + k], acc[w][d]);
            cur[w] = nx;
        }
    }

    size_t rowb = (((size_t)(r * 4 + e) * 4 + kt) * 256 + o0) * 4;
    #pragma unroll
    for (int d = 0; d < 4; ++d) {
        uint4 outv;
        outv.x = (unsigned int)f2bf(acc[0][d]) | ((unsigned int)f2bf(acc[1][d]) << 16);
        outv.y = (unsigned int)f2bf(acc[2][d]) | ((unsigned int)f2bf(acc[3][d]) << 16);
        outv.z = (unsigned int)f2bf(acc[4][d]) | ((unsigned int)f2bf(acc[5][d]) << 16);
        outv.w = (unsigned int)f2bf(acc[6][d]) | ((unsigned int)f2bf(acc[7][d]) << 16);
        Gbf_q[rowb + (size_t)d * 4 + jg] = outv;
    }
}

// ---------------------------------------------------------------- K5m v8: MFMA Toeplitz conv + atomic tanh/r-sum, bnh split (1024 blocks)
__global__ __launch_bounds__(256) void k5m(const short* __restrict__ Gbf,
                                           const float* __restrict__ control,
                                           const float* __restrict__ router,
                                           const float* __restrict__ defo,
                                           const float* __restrict__ gains,
                                           float* __restrict__ out) {
    const int mt_of[20] = {0,1,2,2,3,3,4,4,4,5,5,5,6,6,6,6,7,7,7,7};
    const int kt_of[20] = {0,0,0,1,0,1,0,1,2,0,1,2,0,1,2,3,0,1,2,3};
    __shared__ __align__(16) short Gs[8192];       // 16KB, [ekt 16][lane-linear 64x16B]
    __shared__ __align__(16) float tab[4][130][4]; // 8320B
    __shared__ __align__(16) float wrow[4][128];   // 2KB
    int tid = threadIdx.x;
    int bid = blockIdx.x;                           // 1024 = r(32, XCD-swz) x on(16) x bnh(2)
    int r   = (bid & 7) * 4 + ((bid >> 3) & 3);
    int rest = bid >> 5;
    int on  = rest & 15;
    int bnh = rest >> 4;
    float ga = fabsf(gains[r]);

    // ---- stage G tiles: pre-swizzled source so lane l's fragment sits at byte l*16
    #pragma unroll
    for (int it = 0; it < 4; ++it) {
        int c = it * 256 + tid;
        int ekt = c >> 6;
        int cc = c & 63;
        int o = cc & 15;
        int h = cc >> 4;
        const short* src = Gbf + (((size_t)(r * 16 + ekt) * 256 + on * 16 + o) * 32 + h * 8);
        __builtin_amdgcn_global_load_lds(
            (__attribute__((address_space(1))) const void*)src,
            (__attribute__((address_space(3))) void*)(&Gs[c * 8]), 16, 0, 0);
    }
    // ---- W rows + softmax tab for this bn-half
    for (int i = tid; i < 512; i += 256) {
        int bnl = i >> 7, f = i & 127;
        int bn = bnh * 4 + bnl;
        float s = 0.f;
        #pragma unroll
        for (int cc2 = 0; cc2 < CPD; ++cc2)
            s += control[(bn * CPD + cc2) * CTRL + f] * router[cc2 * N_RES + r];
        wrow[bnl][f] = s;
    }
    for (int i = tid; i < 512; i += 256) {
        int bnl = i >> 7, f = i & 127;
        int bn = bnh * 4 + bnl;
        float v[EXPR]; float mx = -1e30f;
        #pragma unroll
        for (int e = 0; e < EXPR; ++e) {
            float xv = defo[(bn * EXPR + e) * CTRL + f] + (e == 0 ? 1.0f : 0.0f);
            v[e] = xv; mx = fmaxf(mx, xv);
        }
        float sum = 0.f;
        #pragma unroll
        for (int e = 0; e < EXPR; ++e) { v[e] = expf(v[e] - mx); sum += v[e]; }
        float is = 1.0f / sum;
        f32x4 tv = {v[0] * is, v[1] * is, v[2] * is, v[3] * is};
        *(f32x4*)&tab[bnl][f + 1][0] = tv;
    }
    if (tid < 8) {
        int bnl = tid & 3, hi = tid >> 2;
        int bn = bnh * 4 + bnl;
        int f = hi ? 127 : 0;
        int jj = hi ? 129 : 0;
        float v[EXPR]; float mx = -1e30f;
        #pragma unroll
        for (int e = 0; e < EXPR; ++e) {
            float xv = defo[(bn * EXPR + e) * CTRL + f] + (e == 0 ? 1.0f : 0.0f);
            v[e] = xv; mx = fmaxf(mx, xv);
        }
        float sum = 0.f;
        #pragma unroll
        for (int e = 0; e < EXPR; ++e) { v[e] = expf(v[e] - mx); sum += v[e]; }
        float is = 1.0f / sum;
        f32x4 tv = {v[0] * is, v[1] * is, v[2] * is, v[3] * is};
        *(f32x4*)&tab[bnl][jj][0] = tv;
    }
    __syncthreads();

    int l = tid & 63, w = tid >> 6;
    int bn = bnh * 4 + w;
    int n = l & 15, g4 = l >> 4;
    int ocol = on * 16 + n;
    int c = (on < 8) ? -1 : 0;
    float wg = (((float)ocol + 0.5f) * (1.0f / 256.0f) - 0.5f) - (float)c;

    bf16x8 bfr[4][4];
    #pragma unroll
    for (int e = 0; e < 4; ++e)
        #pragma unroll
        for (int kt = 0; kt < 4; ++kt)
            bfr[e][kt] = *(const bf16x8*)&Gs[(e * 4 + kt) * 512 + l * 8];

    bf16x8 wfrag[8];
    #pragma unroll
    for (int b = 0; b < 8; ++b) {
        bf16x8 v;
        #pragma unroll
        for (int ee = 0; ee < 8; ++ee) {
            int diff = b * 16 + n - ((ee >> 2) << 4) - (g4 << 2) - (ee & 3);
            float val = (diff >= 0) ? wrow[w][diff] : 0.f;
            v[ee] = (short)f2bf(val);
        }
        wfrag[b] = v;
    }

    f32x4 acc[4][8] = {};
    #pragma unroll
    for (int pr = 0; pr < 20; ++pr) {
        int mt = mt_of[pr], kt = kt_of[pr];
        int b = mt - 2 * kt;
        #pragma unroll
        for (int e = 0; e < 4; ++e)
            acc[e][mt] = __builtin_amdgcn_mfma_f32_16x16x32_bf16(wfrag[b], bfr[e][kt], acc[e][mt], 0, 0, 0);
    }

    // ---- fused epilogue: de-lerp + e-sum + fast tanh(gain*x) + atomic r-sum
    float* oo = out + (size_t)bn * N_SAMPLES;
    #pragma unroll
    for (int mt = 0; mt < 8; ++mt) {
        int base = mt * 16 + (g4 << 2) + c + 1;
        f32x4 tv[5];
        #pragma unroll
        for (int q = 0; q < 5; ++q)
            tv[q] = *(const f32x4*)&tab[w][base + q][0];
        #pragma unroll
        for (int q = 0; q < 4; ++q) {
            float xv = 0.f;
            #pragma unroll
            for (int e = 0; e < 4; ++e) {
                float de = fmaf(wg, tv[q + 1][e] - tv[q][e], tv[q][e]);
                xv = fmaf(de, acc[e][mt][q], xv);
            }
            int j = mt * 16 + (g4 << 2) + q;
            atomicAdd(&oo[j * STEP + ocol], ftanh(xv * ga));
        }
    }
}

// ---------------------------------------------------------------- launch
extern "C" void kernel_launch(void* const* d_in, const int* in_sizes, int n_in,
                              void* d_out, int out_size, void* d_ws, size_t ws_size,
                              hipStream_t stream) {
    const float* control = (const float*)d_in[0];
    const float* defo    = (const float*)d_in[1];
    const float* router  = (const float*)d_in[2];
    const float* gains   = (const float*)d_in[3];
    const float* amp     = (const float*)d_in[4];
    const float* phase   = (const float*)d_in[5];
    const float* decay   = (const float*)d_in[6];
    const float* noise   = (const float*)d_in[7];

    float* out_summed = (float*)d_out;
    float* out_w      = (float*)d_out + NBN * N_SAMPLES;

    // ws layout:
    //  [0, 8MB): Gbf (k3->k5m)
    //  [8MB, +4KB): normp (k1m->k3)
    //  [16MB, 32.8MB): res_raw f32 (k1m->k3)
    char* ws = (char*)d_ws;
    short* Gbf = (short*)ws;
    float* normp = (float*)(ws + 8388608);
    float* res_raw = (float*)(ws + 16777216);

    k1m<<<1024, 256, 0, stream>>>(amp, phase, decay, res_raw, normp, out_summed);
    k3_impconv<<<640, 256, 0, stream>>>(res_raw, normp, noise, control, router, out_w, (uint4*)Gbf);
    k5m<<<1024, 256, 0, stream>>>(Gbf, control, router, defo, gains, out_summed);
}

// Round 18
// 71.380 us; speedup vs baseline: 1.3242x; 1.3242x over previous
//
#include <hip/hip_runtime.h>
#include <hip/hip_bf16.h>
#include <math.h>

#define N_SAMPLES 32768
#define STEP 256
#define N_FRAMES 128
#define N_COEFFS 257
#define KT 576            // stacked K: 288 (cos) + 288 (sin)
#define NKS 18            // K-steps of 32
#define CPD 16
#define N_RES 32
#define EXPR 4
#define CTRL 128
#define NBN 8
#define BSTR 40           // padded Bs row stride (shorts): 80B -> 8 bank phases
#define PI_F 3.14159265358979323846f

typedef __attribute__((ext_vector_type(8))) short bf16x8;
typedef __attribute__((ext_vector_type(4))) float f32x4;

__device__ __forceinline__ unsigned short f2bf(float x) {
    __hip_bfloat16 h = __float2bfloat16(x);
    return *(unsigned short*)&h;
}

__device__ __forceinline__ float ftanh(float x) {
    float e = exp2f(x * 2.885390081777927f);
    return 1.0f - 2.0f * __builtin_amdgcn_rcpf(e + 1.0f);
}

// ---------------------------------------------------------------- K1m v6: self-contained MFMA GEMM (+ zero out_summed)
__global__ __launch_bounds__(256) void k1m(const float* __restrict__ amp,
                                           const float* __restrict__ phase,
                                           const float* __restrict__ decay,
                                           float* __restrict__ res_raw,
                                           float* __restrict__ normp,
                                           float* __restrict__ out_zero) {
    __shared__ __align__(16) short Bs[2][64 * BSTR];
    __shared__ __align__(16) float Pl[KT];
    __shared__ __align__(16) float Zl[KT];
    __shared__ __align__(16) float Ll[KT];
    __shared__ float red[256];
    int tid = threadIdx.x;
    int l = tid & 63, w = tid >> 6;
    int bid = blockIdx.x;             // 1024, XCD-swizzled on re
    out_zero[(size_t)bid * 256 + tid] = 0.f;
    int x = bid & 7, m = bid >> 3;
    int re = x * 16 + (m >> 3);
    int sub = m & 7;
    int bx = sub >> 1, jb = sub & 1;
    int r = re >> 2, e = re & 3;

    for (int k = tid; k < KT; k += 256) {
        int kk = (k < 288) ? k : k - 288;
        float P = 0.f, Z = 0.f, L2v = 0.f;
        if (kk < N_COEFFS) {
            int src = (r * N_COEFFS + kk) * EXPR + e;
            float mm = fabsf(amp[src]) + 1e-12f;
            float ph = tanhf(phase[src]) * PI_F;
            float sg = 1.0f / (1.0f + expf(-decay[src]));
            float d  = 0.5f + 0.45f * sg;
            float wk = (kk == 0 || kk == 256) ? (1.0f / 512.0f) : (2.0f / 512.0f);
            float c  = (k < 288) ? (wk * mm * cosf(ph)) : (-wk * mm * sinf(ph));
            float sgn = (kk & 1) ? -1.f : 1.f;
            P = c * (d + sgn);
            Z = c * d;
            L2v = log2f(d);
        }
        Pl[k] = P; Zl[k] = Z; Ll[k] = L2v;
    }
    __syncthreads();

    int o = (bx * 4 + w) * 16 + (l & 15);
    int g4v = l >> 4;
    float cb[8], sb[8], cc[8], sc[8];
    #pragma unroll
    for (int ee = 0; ee < 8; ++ee) {
        int delta = ((ee >> 2) << 4) + (g4v << 2) + (ee & 3);
        float ang = (float)((delta * o) & 511) * (2.0f * PI_F / 512.0f);
        sincosf(ang, &sb[ee], &cb[ee]);
        cc[ee] = cb[ee]; sc[ee] = sb[ee];
    }
    float rc, rs;
    {
        float ang = (float)((32 * o) & 511) * (2.0f * PI_F / 512.0f);
        sincosf(ang, &rs, &rc);
    }

    int gj = tid >> 2;
    int gg = tid & 3;
    int jf = jb * 64 + gj;
    float jf_f = (float)jf;

    f32x4 acc[4] = {{0.f,0.f,0.f,0.f},{0.f,0.f,0.f,0.f},{0.f,0.f,0.f,0.f},{0.f,0.f,0.f,0.f}};
    int rrow = l & 15;
    int rcol = (l >> 4) * 8;

    auto GEN = [&](int s, int buf) {
        int kb = s * 32 + gg * 4;
        f32x4 p0 = *(const f32x4*)&Pl[kb];
        f32x4 p1 = *(const f32x4*)&Pl[kb + 16];
        f32x4 z0 = *(const f32x4*)&Zl[kb];
        f32x4 z1 = *(const f32x4*)&Zl[kb + 16];
        f32x4 l0 = *(const f32x4*)&Ll[kb];
        f32x4 l1 = *(const f32x4*)&Ll[kb + 16];
        bf16x8 vv;
        #pragma unroll
        for (int q = 0; q < 4; ++q) {
            float v0 = (jf == 0) ? z0[q] : p0[q] * exp2f(jf_f * l0[q]);
            float v1 = (jf == 0) ? z1[q] : p1[q] * exp2f(jf_f * l1[q]);
            vv[q]     = (short)f2bf(v0);
            vv[4 + q] = (short)f2bf(v1);
        }
        *(bf16x8*)&Bs[buf][gj * BSTR + gg * 8] = vv;
    };

    GEN(0, 0);
    __syncthreads();
    #pragma unroll
    for (int s = 0; s < NKS; ++s) {
        if (s < NKS - 1) GEN(s + 1, (s + 1) & 1);
        if (s == 9) {
            #pragma unroll
            for (int ee = 0; ee < 8; ++ee) { cc[ee] = cb[ee]; sc[ee] = sb[ee]; }
        }
        bf16x8 af;
        #pragma unroll
        for (int ee = 0; ee < 8; ++ee)
            af[ee] = (short)f2bf((s < 9) ? cc[ee] : sc[ee]);
        if (s != 8 && s != NKS - 1) {
            #pragma unroll
            for (int ee = 0; ee < 8; ++ee) {
                float t = cc[ee] * rc - sc[ee] * rs;
                sc[ee] = fmaf(cc[ee], rs, sc[ee] * rc);
                cc[ee] = t;
            }
        }
        const short* bp = &Bs[s & 1][0];
        #pragma unroll
        for (int jt = 0; jt < 4; ++jt) {
            bf16x8 bf = *(const bf16x8*)(bp + (jt * 16 + rrow) * BSTR + rcol);
            acc[jt] = __builtin_amdgcn_mfma_f32_16x16x32_bf16(af, bf, acc[jt], 0, 0, 0);
        }
        __syncthreads();
    }

    int otile = bx * 4 + w;
    int o0 = otile * 16 + ((l >> 4) & 3) * 4;
    int jbase = jb * 64 + (l & 15);
    float s2 = 0.f;
    #pragma unroll
    for (int jt = 0; jt < 4; ++jt) {
        int j = jbase + jt * 16;
        float4 v = make_float4(acc[jt][0], acc[jt][1], acc[jt][2], acc[jt][3]);
        s2 += v.x * v.x + v.y * v.y + v.z * v.z + v.w * v.w;
        *(float4*)&res_raw[(size_t)re * N_SAMPLES + j * STEP + o0] = v;
    }
    red[tid] = s2;
    __syncthreads();
    for (int st = 128; st > 0; st >>= 1) {
        if (tid < st) red[tid] += red[tid + st];
        __syncthreads();
    }
    if (tid == 0) normp[re * 8 + bx * 2 + jb] = red[0];
}

// ---------------------------------------------------------------- K3 v5: sliding-register FIR | route role (out_w)
__global__ __launch_bounds__(256) void k3_impconv(const float* __restrict__ res_raw,
                                                  const float* __restrict__ normp,
                                                  const float* __restrict__ noise,
                                                  const float* __restrict__ control,
                                                  const float* __restrict__ router,
                                                  float* __restrict__ out_w,
                                                  uint4* __restrict__ Gbf_q) {
    __shared__ __align__(16) float st[8320];
    __shared__ __align__(16) float imp[128];
    int bid = blockIdx.x;                 // 640 = 512 FIR (XCD-swizzled on r) + 128 route
    int tid = threadIdx.x;
    if (bid >= 512) {
        int idx = (bid - 512) * 256 + tid;
        int f  = idx % CTRL;
        int r  = (idx / CTRL) % N_RES;
        int bn = idx / (CTRL * N_RES);
        float s = 0.f;
        #pragma unroll
        for (int c = 0; c < CPD; ++c)
            s += control[(bn * CPD + c) * CTRL + f] * router[c * N_RES + r];
        out_w[idx] = s;
        return;
    }
    int r  = (bid & 7) * 4 + ((bid >> 3) & 3);
    int t2 = bid >> 5;
    int e  = t2 & 3;
    int kt = t2 >> 2;
    int re = r * 4 + e;
    float ns = 0.f;
    #pragma unroll
    for (int i = 0; i < 8; ++i) ns += normp[re * 8 + i];
    float inv = 1.0f / (sqrtf(ns) + 1e-8f);
    if (tid < 128)
        imp[tid] = (0.54f - 0.46f * cosf((2.0f * PI_F / 128.0f) * (float)tid)) * noise[tid];
    const float* rp = res_raw + (size_t)re * N_SAMPLES;
    int gbase = kt * 8192 - 127;
    for (int i = tid; i < 8320; i += 256) {
        int g = gbase + i;
        st[i] = (g >= 0 && g < N_SAMPLES) ? rp[g] * inv : 0.f;
    }
    __syncthreads();

    int jg = tid >> 6;
    int o0 = (tid & 63) * 4;
    int jl[8];
    #pragma unroll
    for (int hh = 0; hh < 4; ++hh) {
        int h = jg * 4 + hh;
        int j0 = ((h >> 1) & 1) * 16 + (h >> 2) * 4 + (h & 1) * 2;
        jl[2 * hh] = j0;
        jl[2 * hh + 1] = j0 + 1;
    }
    float4 cur[8];
    float acc[8][4] = {};
    #pragma unroll
    for (int w = 0; w < 8; ++w)
        cur[w] = *(const float4*)&st[jl[w] * 256 + o0];

    for (int v = 0; v < 128; v += 4) {
        float4 im = *(const float4*)&imp[124 - v];
        float wt[4] = {im.w, im.z, im.y, im.x};
        #pragma unroll
        for (int w = 0; w < 8; ++w) {
            float4 nx = *(const float4*)&st[jl[w] * 256 + o0 + v + 4];
            float win[8] = {cur[w].x, cur[w].y, cur[w].z, cur[w].w, nx.x, nx.y, nx.z, nx.w};
            #pragma unroll
            for (int k = 0; k < 4; ++k)
                #pragma unroll
                for (int d = 0; d < 4; ++d)
                    acc[w][d] = fmaf(wt[k], win[d + k], acc[w][d]);
            cur[w] = nx;
        }
    }

    size_t rowb = (((size_t)(r * 4 + e) * 4 + kt) * 256 + o0) * 4;
    #pragma unroll
    for (int d = 0; d < 4; ++d) {
        uint4 outv;
        outv.x = (unsigned int)f2bf(acc[0][d]) | ((unsigned int)f2bf(acc[1][d]) << 16);
        outv.y = (unsigned int)f2bf(acc[2][d]) | ((unsigned int)f2bf(acc[3][d]) << 16);
        outv.z = (unsigned int)f2bf(acc[4][d]) | ((unsigned int)f2bf(acc[5][d]) << 16);
        outv.w = (unsigned int)f2bf(acc[6][d]) | ((unsigned int)f2bf(acc[7][d]) << 16);
        Gbf_q[rowb + (size_t)d * 4 + jg] = outv;
    }
}

// ---------------------------------------------------------------- K5m v9: per-wave r, 4-r LDS reduction, 1 atomic per output
__global__ __launch_bounds__(256) void k5m(const short* __restrict__ Gbf,
                                           const float* __restrict__ control,
                                           const float* __restrict__ router,
                                           const float* __restrict__ defo,
                                           const float* __restrict__ gains,
                                           float* __restrict__ out) {
    const int mt_of[20] = {0,1,2,2,3,3,4,4,4,5,5,5,6,6,6,6,7,7,7,7};
    const int kt_of[20] = {0,0,0,1,0,1,0,1,2,0,1,2,0,1,2,3,0,1,2,3};
    __shared__ __align__(16) float tab[130][4];      // 2080B (single bn)
    __shared__ __align__(16) float wrow[4][128];     // 2KB (per-wave r)
    __shared__ __align__(16) float part[4 * 64 * 33];// 33792B padded partials
    int tid = threadIdx.x;
    int bid = blockIdx.x;                 // 1024 = xcd(8) x on(16) x bn(8)
    int xcd = bid & 7;
    int on  = (bid >> 3) & 15;
    int bn  = bid >> 7;
    int l = tid & 63, w = tid >> 6;
    int r = xcd * 4 + w;                  // wave-private resonator
    float ga = fabsf(gains[r]);

    // ---- per-wave W row (this r, this bn)
    #pragma unroll
    for (int h = 0; h < 2; ++h) {
        int f = h * 64 + l;
        float s = 0.f;
        #pragma unroll
        for (int c2 = 0; c2 < CPD; ++c2)
            s += control[(bn * CPD + c2) * CTRL + f] * router[c2 * N_RES + r];
        wrow[w][f] = s;
    }
    // ---- softmax tab with guard rows (block-shared, rows 0..129)
    if (tid < 130) {
        int f = tid - 1; f = f < 0 ? 0 : (f > 127 ? 127 : f);
        float v[EXPR]; float mx = -1e30f;
        #pragma unroll
        for (int e = 0; e < EXPR; ++e) {
            float xv = defo[(bn * EXPR + e) * CTRL + f] + (e == 0 ? 1.0f : 0.0f);
            v[e] = xv; mx = fmaxf(mx, xv);
        }
        float sum = 0.f;
        #pragma unroll
        for (int e = 0; e < EXPR; ++e) { v[e] = expf(v[e] - mx); sum += v[e]; }
        float is = 1.0f / sum;
        #pragma unroll
        for (int e = 0; e < EXPR; ++e) tab[tid][e] = v[e] * is;
    }
    __syncthreads();

    int n = l & 15, g4 = l >> 4;
    int ocol = on * 16 + n;
    int cofs = (on < 8) ? -1 : 0;
    float wg = (((float)ocol + 0.5f) * (1.0f / 256.0f) - 0.5f) - (float)cofs;

    // ---- wfrag (compressed Toeplitz, from this wave's wrow)
    bf16x8 wfrag[8];
    #pragma unroll
    for (int b = 0; b < 8; ++b) {
        bf16x8 v;
        #pragma unroll
        for (int ee = 0; ee < 8; ++ee) {
            int diff = b * 16 + n - ((ee >> 2) << 4) - (g4 << 2) - (ee & 3);
            float val = (diff >= 0) ? wrow[w][diff] : 0.f;
            v[ee] = (short)f2bf(val);
        }
        wfrag[b] = v;
    }

    // ---- two e-half passes: global coalesced bfr loads (L2-hot, XCD-local)
    const short* gb = Gbf + ((size_t)r * 16) * (256 * 32);
    float xsum[8][4] = {};
    #pragma unroll
    for (int eh = 0; eh < 2; ++eh) {
        bf16x8 bfr[2][4];
        #pragma unroll
        for (int ei = 0; ei < 2; ++ei)
            #pragma unroll
            for (int kt = 0; kt < 4; ++kt) {
                int ekt = (eh * 2 + ei) * 4 + kt;
                bfr[ei][kt] = *(const bf16x8*)(gb + ((size_t)ekt * 256 + ocol) * 32 + g4 * 8);
            }
        f32x4 acc[2][8] = {};
        #pragma unroll
        for (int pr = 0; pr < 20; ++pr) {
            int mt = mt_of[pr], kt = kt_of[pr];
            int b = mt - 2 * kt;
            acc[0][mt] = __builtin_amdgcn_mfma_f32_16x16x32_bf16(wfrag[b], bfr[0][kt], acc[0][mt], 0, 0, 0);
            acc[1][mt] = __builtin_amdgcn_mfma_f32_16x16x32_bf16(wfrag[b], bfr[1][kt], acc[1][mt], 0, 0, 0);
        }
        #pragma unroll
        for (int mt = 0; mt < 8; ++mt) {
            int base = mt * 16 + (g4 << 2) + cofs + 1;
            f32x4 tv[5];
            #pragma unroll
            for (int q = 0; q < 5; ++q)
                tv[q] = *(const f32x4*)&tab[base + q][0];
            #pragma unroll
            for (int q = 0; q < 4; ++q) {
                #pragma unroll
                for (int ei = 0; ei < 2; ++ei) {
                    int e = eh * 2 + ei;
                    float de = fmaf(wg, tv[q + 1][e] - tv[q][e], tv[q][e]);
                    xsum[mt][q] = fmaf(de, acc[ei][mt][q], xsum[mt][q]);
                }
            }
        }
    }

    // ---- tanh + partials to LDS (stride-33 padding: conflict-free)
    float* myp = &part[(w * 64 + l) * 33];
    #pragma unroll
    for (int mt = 0; mt < 8; ++mt)
        #pragma unroll
        for (int q = 0; q < 4; ++q)
            myp[mt * 4 + q] = ftanh(xsum[mt][q] * ga);
    __syncthreads();

    // ---- 4-r reduction + single atomic per output
    int rn = tid & 15, jgr = tid >> 4;    // 16 n x 16 j-groups
    float* ob = out + (size_t)bn * N_SAMPLES + on * 16 + rn;
    #pragma unroll
    for (int jj = 0; jj < 8; ++jj) {
        int j = jgr * 8 + jj;
        int mt = j >> 4, rem = j & 15;
        int gg4 = rem >> 2, q = rem & 3;
        int ll = gg4 * 16 + rn;
        int idx = mt * 4 + q;
        float s = part[ll * 33 + idx]
                + part[(64 + ll) * 33 + idx]
                + part[(128 + ll) * 33 + idx]
                + part[(192 + ll) * 33 + idx];
        atomicAdd(ob + j * STEP, s);
    }
}

// ---------------------------------------------------------------- launch
extern "C" void kernel_launch(void* const* d_in, const int* in_sizes, int n_in,
                              void* d_out, int out_size, void* d_ws, size_t ws_size,
                              hipStream_t stream) {
    const float* control = (const float*)d_in[0];
    const float* defo    = (const float*)d_in[1];
    const float* router  = (const float*)d_in[2];
    const float* gains   = (const float*)d_in[3];
    const float* amp     = (const float*)d_in[4];
    const float* phase   = (const float*)d_in[5];
    const float* decay   = (const float*)d_in[6];
    const float* noise   = (const float*)d_in[7];

    float* out_summed = (float*)d_out;
    float* out_w      = (float*)d_out + NBN * N_SAMPLES;

    // ws layout:
    //  [0, 8MB): Gbf (k3->k5m)
    //  [8MB, +4KB): normp (k1m->k3)
    //  [16MB, 32.8MB): res_raw f32 (k1m->k3)
    char* ws = (char*)d_ws;
    short* Gbf = (short*)ws;
    float* normp = (float*)(ws + 8388608);
    float* res_raw = (float*)(ws + 16777216);

    k1m<<<1024, 256, 0, stream>>>(amp, phase, decay, res_raw, normp, out_summed);
    k3_impconv<<<640, 256, 0, stream>>>(res_raw, normp, noise, control, router, out_w, (uint4*)Gbf);
    k5m<<<1024, 256, 0, stream>>>(Gbf, control, router, defo, gains, out_summed);
}

// Round 19
// 71.374 us; speedup vs baseline: 1.3243x; 1.0001x over previous
//
#include <hip/hip_runtime.h>
#include <hip/hip_bf16.h>
#include <math.h>

#define N_SAMPLES 32768
#define STEP 256
#define N_FRAMES 128
#define N_COEFFS 257
#define KT 576            // stacked K: 288 (cos) + 288 (sin)
#define NKS 18            // K-steps of 32
#define CPD 16
#define N_RES 32
#define EXPR 4
#define CTRL 128
#define NBN 8
#define BSTR 40           // padded Bs row stride (shorts): 80B -> 8 bank phases
#define PI_F 3.14159265358979323846f

typedef __attribute__((ext_vector_type(8))) short bf16x8;
typedef __attribute__((ext_vector_type(4))) float f32x4;

__device__ __forceinline__ unsigned short f2bf(float x) {
    __hip_bfloat16 h = __float2bfloat16(x);
    return *(unsigned short*)&h;
}

__device__ __forceinline__ float bf2f(short u) {
    return __bfloat162float(*(__hip_bfloat16*)&u);
}

__device__ __forceinline__ float ftanh(float x) {
    float e = exp2f(x * 2.885390081777927f);
    return 1.0f - 2.0f * __builtin_amdgcn_rcpf(e + 1.0f);
}

// ---------------------------------------------------------------- K1m v7: MFMA GEMM, packed/permuted params + cos-table init
__global__ __launch_bounds__(256) void k1m(const float* __restrict__ amp,
                                           const float* __restrict__ phase,
                                           const float* __restrict__ decay,
                                           float* __restrict__ res_raw,
                                           float* __restrict__ normp,
                                           float* __restrict__ out_zero) {
    __shared__ __align__(16) short Bs[2][64 * BSTR];
    __shared__ __align__(16) short Pb[KT];       // bf16, permuted slot order
    __shared__ __align__(16) short Zb[KT];       // bf16, permuted slot order
    __shared__ __align__(16) float Lf[KT];       // f32, permuted slot order
    __shared__ __align__(16) float costab[512];
    __shared__ float red[256];
    int tid = threadIdx.x;
    int l = tid & 63, w = tid >> 6;
    int bid = blockIdx.x;             // 1024, XCD-swizzled on re
    out_zero[(size_t)bid * 256 + tid] = 0.f;
    int x = bid & 7, m = bid >> 3;
    int re = x * 16 + (m >> 3);
    int sub = m & 7;
    int bx = sub >> 1, jb = sub & 1;
    int r = re >> 2, e = re & 3;

    // ---- cos table (angles are the exact quantized set used before)
    for (int i = tid; i < 512; i += 256)
        costab[i] = cosf((float)i * (2.0f * PI_F / 512.0f));

    // ---- per-block params, written in permuted B-slot order
    for (int k = tid; k < KT; k += 256) {
        int kk = (k < 288) ? k : k - 288;
        float P = 0.f, Z = 0.f, L2v = 0.f;
        if (kk < N_COEFFS) {
            int src = (r * N_COEFFS + kk) * EXPR + e;
            float mm = fabsf(amp[src]) + 1e-12f;
            float ph = tanhf(phase[src]) * PI_F;
            float sg = 1.0f / (1.0f + expf(-decay[src]));
            float d  = 0.5f + 0.45f * sg;
            float wk = (kk == 0 || kk == 256) ? (1.0f / 512.0f) : (2.0f / 512.0f);
            float c  = (k < 288) ? (wk * mm * cosf(ph)) : (-wk * mm * sinf(ph));
            float sgn = (kk & 1) ? -1.f : 1.f;
            P = c * (d + sgn);
            Z = c * d;
            L2v = log2f(d);
        }
        int kloc = k & 31, blk = k >> 5;
        int p = blk * 32 + ((kloc >> 2) & 3) * 8 + ((kloc >> 4) & 1) * 4 + (kloc & 3);
        Pb[p] = (short)f2bf(P);
        Zb[p] = (short)f2bf(Z);
        Lf[p] = L2v;
    }
    __syncthreads();

    // ---- twiddle init via table (bit-identical args to prior sincosf)
    int o = (bx * 4 + w) * 16 + (l & 15);
    int g4v = l >> 4;
    float cb[8], sb[8], cc[8], sc[8];
    #pragma unroll
    for (int ee = 0; ee < 8; ++ee) {
        int delta = ((ee >> 2) << 4) + (g4v << 2) + (ee & 3);
        int xx = (delta * o) & 511;
        cb[ee] = costab[xx];
        sb[ee] = costab[(xx + 384) & 511];   // sin(t) = cos(t - pi/2)
        cc[ee] = cb[ee]; sc[ee] = sb[ee];
    }
    float rc, rs;
    {
        int xr = (32 * o) & 511;
        rc = costab[xr];
        rs = costab[(xr + 384) & 511];
    }

    int gj = tid >> 2;
    int gg = tid & 3;
    int jf = jb * 64 + gj;
    float jf_f = (float)jf;

    f32x4 acc[4] = {{0.f,0.f,0.f,0.f},{0.f,0.f,0.f,0.f},{0.f,0.f,0.f,0.f},{0.f,0.f,0.f,0.f}};
    int rrow = l & 15;
    int rcol = (l >> 4) * 8;

    auto GEN = [&](int s, int buf) {
        int kbp = s * 32 + gg * 8;
        bf16x8 vv;
        if (jf == 0) {
            vv = *(const bf16x8*)&Zb[kbp];
        } else {
            bf16x8 Pp = *(const bf16x8*)&Pb[kbp];
            f32x4 l0 = *(const f32x4*)&Lf[kbp];
            f32x4 l1 = *(const f32x4*)&Lf[kbp + 4];
            #pragma unroll
            for (int q = 0; q < 4; ++q) {
                vv[q]     = (short)f2bf(bf2f(Pp[q])     * exp2f(jf_f * l0[q]));
                vv[4 + q] = (short)f2bf(bf2f(Pp[4 + q]) * exp2f(jf_f * l1[q]));
            }
        }
        *(bf16x8*)&Bs[buf][gj * BSTR + gg * 8] = vv;
    };

    GEN(0, 0);
    __syncthreads();
    #pragma unroll
    for (int s = 0; s < NKS; ++s) {
        if (s < NKS - 1) GEN(s + 1, (s + 1) & 1);
        if (s == 9) {
            #pragma unroll
            for (int ee = 0; ee < 8; ++ee) { cc[ee] = cb[ee]; sc[ee] = sb[ee]; }
        }
        bf16x8 af;
        #pragma unroll
        for (int ee = 0; ee < 8; ++ee)
            af[ee] = (short)f2bf((s < 9) ? cc[ee] : sc[ee]);
        if (s != 8 && s != NKS - 1) {
            #pragma unroll
            for (int ee = 0; ee < 8; ++ee) {
                float t = cc[ee] * rc - sc[ee] * rs;
                sc[ee] = fmaf(cc[ee], rs, sc[ee] * rc);
                cc[ee] = t;
            }
        }
        const short* bp = &Bs[s & 1][0];
        #pragma unroll
        for (int jt = 0; jt < 4; ++jt) {
            bf16x8 bf = *(const bf16x8*)(bp + (jt * 16 + rrow) * BSTR + rcol);
            acc[jt] = __builtin_amdgcn_mfma_f32_16x16x32_bf16(af, bf, acc[jt], 0, 0, 0);
        }
        __syncthreads();
    }

    int otile = bx * 4 + w;
    int o0 = otile * 16 + ((l >> 4) & 3) * 4;
    int jbase = jb * 64 + (l & 15);
    float s2 = 0.f;
    #pragma unroll
    for (int jt = 0; jt < 4; ++jt) {
        int j = jbase + jt * 16;
        float4 v = make_float4(acc[jt][0], acc[jt][1], acc[jt][2], acc[jt][3]);
        s2 += v.x * v.x + v.y * v.y + v.z * v.z + v.w * v.w;
        *(float4*)&res_raw[(size_t)re * N_SAMPLES + j * STEP + o0] = v;
    }
    red[tid] = s2;
    __syncthreads();
    for (int st = 128; st > 0; st >>= 1) {
        if (tid < st) red[tid] += red[tid + st];
        __syncthreads();
    }
    if (tid == 0) normp[re * 8 + bx * 2 + jb] = red[0];
}

// ---------------------------------------------------------------- K3 v5: sliding-register FIR | route role (out_w)
__global__ __launch_bounds__(256) void k3_impconv(const float* __restrict__ res_raw,
                                                  const float* __restrict__ normp,
                                                  const float* __restrict__ noise,
                                                  const float* __restrict__ control,
                                                  const float* __restrict__ router,
                                                  float* __restrict__ out_w,
                                                  uint4* __restrict__ Gbf_q) {
    __shared__ __align__(16) float st[8320];
    __shared__ __align__(16) float imp[128];
    int bid = blockIdx.x;                 // 640 = 512 FIR (XCD-swizzled on r) + 128 route
    int tid = threadIdx.x;
    if (bid >= 512) {
        int idx = (bid - 512) * 256 + tid;
        int f  = idx % CTRL;
        int r  = (idx / CTRL) % N_RES;
        int bn = idx / (CTRL * N_RES);
        float s = 0.f;
        #pragma unroll
        for (int c = 0; c < CPD; ++c)
            s += control[(bn * CPD + c) * CTRL + f] * router[c * N_RES + r];
        out_w[idx] = s;
        return;
    }
    int r  = (bid & 7) * 4 + ((bid >> 3) & 3);
    int t2 = bid >> 5;
    int e  = t2 & 3;
    int kt = t2 >> 2;
    int re = r * 4 + e;
    float ns = 0.f;
    #pragma unroll
    for (int i = 0; i < 8; ++i) ns += normp[re * 8 + i];
    float inv = 1.0f / (sqrtf(ns) + 1e-8f);
    if (tid < 128)
        imp[tid] = (0.54f - 0.46f * cosf((2.0f * PI_F / 128.0f) * (float)tid)) * noise[tid];
    const float* rp = res_raw + (size_t)re * N_SAMPLES;
    int gbase = kt * 8192 - 127;
    for (int i = tid; i < 8320; i += 256) {
        int g = gbase + i;
        st[i] = (g >= 0 && g < N_SAMPLES) ? rp[g] * inv : 0.f;
    }
    __syncthreads();

    int jg = tid >> 6;
    int o0 = (tid & 63) * 4;
    int jl[8];
    #pragma unroll
    for (int hh = 0; hh < 4; ++hh) {
        int h = jg * 4 + hh;
        int j0 = ((h >> 1) & 1) * 16 + (h >> 2) * 4 + (h & 1) * 2;
        jl[2 * hh] = j0;
        jl[2 * hh + 1] = j0 + 1;
    }
    float4 cur[8];
    float acc[8][4] = {};
    #pragma unroll
    for (int w = 0; w < 8; ++w)
        cur[w] = *(const float4*)&st[jl[w] * 256 + o0];

    for (int v = 0; v < 128; v += 4) {
        float4 im = *(const float4*)&imp[124 - v];
        float wt[4] = {im.w, im.z, im.y, im.x};
        #pragma unroll
        for (int w = 0; w < 8; ++w) {
            float4 nx = *(const float4*)&st[jl[w] * 256 + o0 + v + 4];
            float win[8] = {cur[w].x, cur[w].y, cur[w].z, cur[w].w, nx.x, nx.y, nx.z, nx.w};
            #pragma unroll
            for (int k = 0; k < 4; ++k)
                #pragma unroll
                for (int d = 0; d < 4; ++d)
                    acc[w][d] = fmaf(wt[k], win[d + k], acc[w][d]);
            cur[w] = nx;
        }
    }

    size_t rowb = (((size_t)(r * 4 + e) * 4 + kt) * 256 + o0) * 4;
    #pragma unroll
    for (int d = 0; d < 4; ++d) {
        uint4 outv;
        outv.x = (unsigned int)f2bf(acc[0][d]) | ((unsigned int)f2bf(acc[1][d]) << 16);
        outv.y = (unsigned int)f2bf(acc[2][d]) | ((unsigned int)f2bf(acc[3][d]) << 16);
        outv.z = (unsigned int)f2bf(acc[4][d]) | ((unsigned int)f2bf(acc[5][d]) << 16);
        outv.w = (unsigned int)f2bf(acc[6][d]) | ((unsigned int)f2bf(acc[7][d]) << 16);
        Gbf_q[rowb + (size_t)d * 4 + jg] = outv;
    }
}

// ---------------------------------------------------------------- K5m v9: per-wave r, 4-r LDS reduction, 1 atomic per output
__global__ __launch_bounds__(256) void k5m(const short* __restrict__ Gbf,
                                           const float* __restrict__ control,
                                           const float* __restrict__ router,
                                           const float* __restrict__ defo,
                                           const float* __restrict__ gains,
                                           float* __restrict__ out) {
    const int mt_of[20] = {0,1,2,2,3,3,4,4,4,5,5,5,6,6,6,6,7,7,7,7};
    const int kt_of[20] = {0,0,0,1,0,1,0,1,2,0,1,2,0,1,2,3,0,1,2,3};
    __shared__ __align__(16) float tab[130][4];
    __shared__ __align__(16) float wrow[4][128];
    __shared__ __align__(16) float part[4 * 64 * 33];
    int tid = threadIdx.x;
    int bid = blockIdx.x;                 // 1024 = xcd(8) x on(16) x bn(8)
    int xcd = bid & 7;
    int on  = (bid >> 3) & 15;
    int bn  = bid >> 7;
    int l = tid & 63, w = tid >> 6;
    int r = xcd * 4 + w;
    float ga = fabsf(gains[r]);

    #pragma unroll
    for (int h = 0; h < 2; ++h) {
        int f = h * 64 + l;
        float s = 0.f;
        #pragma unroll
        for (int c2 = 0; c2 < CPD; ++c2)
            s += control[(bn * CPD + c2) * CTRL + f] * router[c2 * N_RES + r];
        wrow[w][f] = s;
    }
    if (tid < 130) {
        int f = tid - 1; f = f < 0 ? 0 : (f > 127 ? 127 : f);
        float v[EXPR]; float mx = -1e30f;
        #pragma unroll
        for (int e = 0; e < EXPR; ++e) {
            float xv = defo[(bn * EXPR + e) * CTRL + f] + (e == 0 ? 1.0f : 0.0f);
            v[e] = xv; mx = fmaxf(mx, xv);
        }
        float sum = 0.f;
        #pragma unroll
        for (int e = 0; e < EXPR; ++e) { v[e] = expf(v[e] - mx); sum += v[e]; }
        float is = 1.0f / sum;
        #pragma unroll
        for (int e = 0; e < EXPR; ++e) tab[tid][e] = v[e] * is;
    }
    __syncthreads();

    int n = l & 15, g4 = l >> 4;
    int ocol = on * 16 + n;
    int cofs = (on < 8) ? -1 : 0;
    float wg = (((float)ocol + 0.5f) * (1.0f / 256.0f) - 0.5f) - (float)cofs;

    bf16x8 wfrag[8];
    #pragma unroll
    for (int b = 0; b < 8; ++b) {
        bf16x8 v;
        #pragma unroll
        for (int ee = 0; ee < 8; ++ee) {
            int diff = b * 16 + n - ((ee >> 2) << 4) - (g4 << 2) - (ee & 3);
            float val = (diff >= 0) ? wrow[w][diff] : 0.f;
            v[ee] = (short)f2bf(val);
        }
        wfrag[b] = v;
    }

    const short* gb = Gbf + ((size_t)r * 16) * (256 * 32);
    float xsum[8][4] = {};
    #pragma unroll
    for (int eh = 0; eh < 2; ++eh) {
        bf16x8 bfr[2][4];
        #pragma unroll
        for (int ei = 0; ei < 2; ++ei)
            #pragma unroll
            for (int kt = 0; kt < 4; ++kt) {
                int ekt = (eh * 2 + ei) * 4 + kt;
                bfr[ei][kt] = *(const bf16x8*)(gb + ((size_t)ekt * 256 + ocol) * 32 + g4 * 8);
            }
        f32x4 acc[2][8] = {};
        #pragma unroll
        for (int pr = 0; pr < 20; ++pr) {
            int mt = mt_of[pr], kt = kt_of[pr];
            int b = mt - 2 * kt;
            acc[0][mt] = __builtin_amdgcn_mfma_f32_16x16x32_bf16(wfrag[b], bfr[0][kt], acc[0][mt], 0, 0, 0);
            acc[1][mt] = __builtin_amdgcn_mfma_f32_16x16x32_bf16(wfrag[b], bfr[1][kt], acc[1][mt], 0, 0, 0);
        }
        #pragma unroll
        for (int mt = 0; mt < 8; ++mt) {
            int base = mt * 16 + (g4 << 2) + cofs + 1;
            f32x4 tv[5];
            #pragma unroll
            for (int q = 0; q < 5; ++q)
                tv[q] = *(const f32x4*)&tab[base + q][0];
            #pragma unroll
            for (int q = 0; q < 4; ++q) {
                #pragma unroll
                for (int ei = 0; ei < 2; ++ei) {
                    int e = eh * 2 + ei;
                    float de = fmaf(wg, tv[q + 1][e] - tv[q][e], tv[q][e]);
                    xsum[mt][q] = fmaf(de, acc[ei][mt][q], xsum[mt][q]);
                }
            }
        }
    }

    float* myp = &part[(w * 64 + l) * 33];
    #pragma unroll
    for (int mt = 0; mt < 8; ++mt)
        #pragma unroll
        for (int q = 0; q < 4; ++q)
            myp[mt * 4 + q] = ftanh(xsum[mt][q] * ga);
    __syncthreads();

    int rn = tid & 15, jgr = tid >> 4;
    float* ob = out + (size_t)bn * N_SAMPLES + on * 16 + rn;
    #pragma unroll
    for (int jj = 0; jj < 8; ++jj) {
        int j = jgr * 8 + jj;
        int mt = j >> 4, rem = j & 15;
        int gg4 = rem >> 2, q = rem & 3;
        int ll = gg4 * 16 + rn;
        int idx = mt * 4 + q;
        float s = part[ll * 33 + idx]
                + part[(64 + ll) * 33 + idx]
                + part[(128 + ll) * 33 + idx]
                + part[(192 + ll) * 33 + idx];
        atomicAdd(ob + j * STEP, s);
    }
}

// ---------------------------------------------------------------- launch
extern "C" void kernel_launch(void* const* d_in, const int* in_sizes, int n_in,
                              void* d_out, int out_size, void* d_ws, size_t ws_size,
                              hipStream_t stream) {
    const float* control = (const float*)d_in[0];
    const float* defo    = (const float*)d_in[1];
    const float* router  = (const float*)d_in[2];
    const float* gains   = (const float*)d_in[3];
    const float* amp     = (const float*)d_in[4];
    const float* phase   = (const float*)d_in[5];
    const float* decay   = (const float*)d_in[6];
    const float* noise   = (const float*)d_in[7];

    float* out_summed = (float*)d_out;
    float* out_w      = (float*)d_out + NBN * N_SAMPLES;

    // ws layout:
    //  [0, 8MB): Gbf (k3->k5m)
    //  [8MB, +4KB): normp (k1m->k3)
    //  [16MB, 32.8MB): res_raw f32 (k1m->k3)
    char* ws = (char*)d_ws;
    short* Gbf = (short*)ws;
    float* normp = (float*)(ws + 8388608);
    float* res_raw = (float*)(ws + 16777216);

    k1m<<<1024, 256, 0, stream>>>(amp, phase, decay, res_raw, normp, out_summed);
    k3_impconv<<<640, 256, 0, stream>>>(res_raw, normp, noise, control, router, out_w, (uint4*)Gbf);
    k5m<<<1024, 256, 0, stream>>>(Gbf, control, router, defo, gains, out_summed);
}